// Round 7
// baseline (1934.881 us; speedup 1.0000x reference)
//
#include <hip/hip_runtime.h>
#include <math.h>

constexpr int NY_ = 320, NX_ = 320, NT_ = 160, SHOTS_ = 2, NSRC_ = 8, NREC_ = 96;
constexpr float DT_  = 4.0e-4f;
constexpr float C1_  = 9.0f / 8.0f;
constexpr float C2_  = -1.0f / 24.0f;
constexpr float IDH_ = 0.25f;           // 1/DH, exact
constexpr int NSTRIP_ = 40;             // 8-row strips per shot
constexpr int NBLK_   = SHOTS_ * NSTRIP_;
// Compact publish slots: per (parity, shot, strip) 15 rows x 320:
//   slots 0-2: syy rows r0,r0+1,r0+2   slots 3-5: syy rows r0+5,r0+6,r0+7
//   slots 6-8: sxy rows r0..r0+2       slots 9-11: sxy rows r0+5..r0+7
//   slot 12: sxx row r0                slots 13,14: sxx rows r0+6,r0+7
constexpr int HSLOT_   = 15 * NX_;
constexpr int REC_OFF_ = 2 * SHOTS_ * NSTRIP_ * HSLOT_;        // 768000 floats
constexpr int FLG_OFF_ = REC_OFF_ + SHOTS_ * NREC_ * NT_;      // +30720
constexpr int WS_WORDS_ = FLG_OFF_ + 256;

__device__ __forceinline__ int hoff(int p, int s, int j) {
    return ((p * SHOTS_ + s) * NSTRIP_ + j) * HSLOT_;
}

// ---- coherent (IF-backed) access: relaxed agent-scope atomics -> sc0 sc1,
// bypass L1/L2, served at the agent coherence point. No cache flushes needed.
__device__ __forceinline__ float cld(const float* p) {
    return __hip_atomic_load(p, __ATOMIC_RELAXED, __HIP_MEMORY_SCOPE_AGENT);
}
__device__ __forceinline__ void cst(float* p, float v) {
    __hip_atomic_store(p, v, __ATOMIC_RELAXED, __HIP_MEMORY_SCOPE_AGENT);
}
__device__ __forceinline__ unsigned cldu(const unsigned* p) {
    return __hip_atomic_load(p, __ATOMIC_RELAXED, __HIP_MEMORY_SCOPE_AGENT);
}
__device__ __forceinline__ void cstu(unsigned* p, unsigned v) {
    __hip_atomic_store(p, v, __ATOMIC_RELAXED, __HIP_MEMORY_SCOPE_AGENT);
}

// guarded LDS x-tap: out-of-grid cols read 0 (jnp.roll-wrap lands in the
// 2-wide masked-zero border -> exactly equivalent; verified rounds 2-6)
template <int R>
__device__ __forceinline__ float ltap(const float (*A)[NX_], int ly, int c) {
    return ((unsigned)c < (unsigned)NX_) ? A[ly][c] : 0.0f;
}
// register x-tap via wave shuffle (cells 64-col interleaved per thread)
__device__ __forceinline__ float shtap(float cur, float adj, int lane, int dx) {
    int idx = (lane + dx) & 63;
    float a = __shfl(cur, idx, 64);
    float b = __shfl(adj, idx, 64);
    return ((unsigned)(lane + dx) < 64u) ? a : b;
}

// P2P neighbor sync (round-5/6-verified pattern): wave 0 polls j+/-1 flags.
__device__ __forceinline__ void pollNbr(const unsigned* f, int sbase, int j,
                                        unsigned tgt, int tid) {
    __syncthreads();
    if (tid < 64) {
        for (;;) {
            bool ok = true;
            if (tid == 0 && j > 0)                ok = cldu(&f[sbase + j - 1]) >= tgt;
            else if (tid == 1 && j < NSTRIP_ - 1) ok = cldu(&f[sbase + j + 1]) >= tgt;
            if (__all(ok)) break;
            __builtin_amdgcn_s_sleep(1);
        }
    }
    __syncthreads();
    asm volatile("" ::: "memory");
}

__global__ void init_kernel(float* __restrict__ ws) {
    for (int i = blockIdx.x * 256 + threadIdx.x; i < WS_WORDS_; i += gridDim.x * 256)
        ws[i] = 0.0f;
}

__global__ __launch_bounds__(768)
void elastic_kernel(const float* __restrict__ lamb, const float* __restrict__ mu,
                    const float* __restrict__ buoy, const float* __restrict__ amps,
                    const int* __restrict__ src_loc, const int* __restrict__ rec_loc,
                    float* __restrict__ out, float* __restrict__ ws)
{
    // Extended stress region rows [r0-3, r0+10] -> LDS rows 0..13.
    // Velocity: vy rows [r0-1, r0+9] -> Lvy 0..10; vx rows [r0-2, r0+8] -> Lvx 0..10.
    __shared__ float Lsyy[14][NX_], Lsxy[14][NX_], Lvy[11][NX_], Lvx[11][NX_];

    const int tid  = threadIdx.x;
    const int lane = tid & 63;
    const int w    = tid >> 6;          // wave = row index, 12 waves
    const int bid  = blockIdx.x;
    const int s    = bid / NSTRIP_;
    const int j    = bid % NSTRIP_;
    const int r0   = j * 8;
    const int gy   = r0 - 2 + w;        // this wave's global row (r0-2 .. r0+9)
    const int ys   = w + 1;             // stress LDS row for gy
    const bool doVy = (w >= 1);         // vy computed on rows r0-1..r0+9
    const bool doVx = (w <= 10);        // vx computed on rows r0-2..r0+8
    const bool doS  = (w >= 2 && w <= 9);  // stress on owned rows r0..r0+7

    float* H = ws;                                   // publish slots
    float* recp = ws + REC_OFF_ + (s * NREC_ + tid) * NT_;   // valid if tid<96
    unsigned* flg = (unsigned*)(ws + FLG_OFF_);
    const int sbase = s * NSTRIP_;

    // --- loop invariants (double-precision PML to match numpy) ---
    const double d0 = 3.0 * 1600.0 * log(1000.0) / (2.0 * 20.0 * 4.0);
    double py = 0.0;
    if (gy < 20)             { double u = (20.0 - gy) / 20.0;           py = u * u; }
    else if (gy >= NY_ - 20) { double u = (gy - (NY_ - 1 - 20)) / 20.0; py = u * u; }
    const float by = (float)exp(-d0 * py * 4.0e-4);
    const float bym1 = by - 1.0f;
    const int gyc = gy < 0 ? 0 : (gy > NY_ - 1 ? NY_ - 1 : gy);   // clamp for material loads

    float bx[5], bxm1[5], mk[5], la[5], muv[5], bu[5], l2m[5];
    #pragma unroll
    for (int k = 0; k < 5; ++k) {
        int c = 64 * k + lane;
        double px = 0.0;
        if (c < 20)             { double u = (20.0 - c) / 20.0;           px = u * u; }
        else if (c >= NX_ - 20) { double u = (c - (NX_ - 1 - 20)) / 20.0; px = u * u; }
        bx[k] = (float)exp(-d0 * px * 4.0e-4);
        bxm1[k] = bx[k] - 1.0f;
        mk[k] = (gy < 2 || gy >= NY_ - 2 || c < 2 || c >= NX_ - 2) ? 0.0f : 1.0f;
        la[k]  = lamb[gyc * NX_ + c];
        muv[k] = mu[gyc * NX_ + c];
        bu[k]  = buoy[gyc * NX_ + c];
        l2m[k] = la[k] + 2.0f * muv[k];
    }

    // source mask (halo rows included -> redundancy-consistent injection)
    unsigned long long sm = 0ull;
    for (int js = 0; js < NSRC_; ++js) {
        int sy = src_loc[(s * NSRC_ + js) * 2 + 0];
        int sx = src_loc[(s * NSRC_ + js) * 2 + 1];
        if (sy == gy && (sx & 63) == lane) sm |= 1ull << (8 * (sx >> 6) + js);
    }
    bool myrec = false; int rrow = 0, rx = 0;
    if (tid < NREC_) {
        int ry = rec_loc[(s * NREC_ + tid) * 2 + 0];
        rx     = rec_loc[(s * NREC_ + tid) * 2 + 1];
        if ((ry >> 3) == j) { myrec = true; rrow = ry - r0 + 1; }   // Lvy row
    }

    // zero LDS (boundary-strip halo rows rely on these zeros persisting)
    for (int i = tid; i < 14 * NX_; i += 768) { ((float*)Lsyy)[i] = 0.f; ((float*)Lsxy)[i] = 0.f; }
    for (int i = tid; i < 11 * NX_; i += 768) { ((float*)Lvy)[i] = 0.f; ((float*)Lvx)[i] = 0.f; }

    // register state for this wave's row
    float vy[5] = {}, vx[5] = {}, syy[5] = {}, sxy[5] = {}, sxx[5] = {};
    float msyyy[5] = {}, msxyy[5] = {}, msxyx[5] = {}, msxxx[5] = {};
    float mvyy[5] = {}, mvyx[5] = {}, mvxy[5] = {}, mvxx[5] = {};

    for (int t = 0; t < NT_; ++t) {
        // ---- one sync point per timestep: neighbors' stress(t-1) published ----
        pollNbr(flg, sbase, j, (unsigned)t, tid);
        const int pi = (t + 1) & 1;     // import parity ((t-1)&1)
        const int po = t & 1;           // publish parity

        // import stress halos into LDS (12 rows) -- zeros persist at grid edges
        if (tid < NX_) {
            int c = tid;
            if (j > 0) {
                const float* b = H + hoff(pi, s, j - 1);
                float a0 = cld(b + 3 * NX_ + c), a1 = cld(b + 4 * NX_ + c), a2 = cld(b + 5 * NX_ + c);
                float d0_ = cld(b + 9 * NX_ + c), d1 = cld(b + 10 * NX_ + c), d2 = cld(b + 11 * NX_ + c);
                Lsyy[0][c] = a0; Lsyy[1][c] = a1; Lsyy[2][c] = a2;
                Lsxy[0][c] = d0_; Lsxy[1][c] = d1; Lsxy[2][c] = d2;
            }
            if (j < NSTRIP_ - 1) {
                const float* b = H + hoff(pi, s, j + 1);
                float a0 = cld(b + 0 * NX_ + c), a1 = cld(b + 1 * NX_ + c), a2 = cld(b + 2 * NX_ + c);
                float d0_ = cld(b + 6 * NX_ + c), d1 = cld(b + 7 * NX_ + c), d2 = cld(b + 8 * NX_ + c);
                Lsyy[11][c] = a0; Lsyy[12][c] = a1; Lsyy[13][c] = a2;
                Lsxy[11][c] = d0_; Lsxy[12][c] = d1; Lsxy[13][c] = d2;
            }
        }
        // sxx register import for halo waves (rows r0-2, r0-1, r0+8)
        if (w == 0 && j > 0) {
            const float* b = H + hoff(pi, s, j - 1) + 13 * NX_;
            #pragma unroll
            for (int k = 0; k < 5; ++k) sxx[k] = cld(b + 64 * k + lane);
        } else if (w == 1 && j > 0) {
            const float* b = H + hoff(pi, s, j - 1) + 14 * NX_;
            #pragma unroll
            for (int k = 0; k < 5; ++k) sxx[k] = cld(b + 64 * k + lane);
        } else if (w == 10 && j < NSTRIP_ - 1) {
            const float* b = H + hoff(pi, s, j + 1) + 12 * NX_;
            #pragma unroll
            for (int k = 0; k < 5; ++k) sxx[k] = cld(b + 64 * k + lane);
        }
        __syncthreads();

        // ---- velocity update (owned + redundant halo rows) ----
        if (doVy) {
            #pragma unroll
            for (int k = 0; k < 5; ++k) {
                const int c = 64 * k + lane;
                float d, ay;
                d = (C1_ * (Lsyy[ys][c] - Lsyy[ys - 1][c]) + C2_ * (Lsyy[ys + 1][c] - Lsyy[ys - 2][c])) * IDH_;
                msyyy[k] = by * msyyy[k] + bym1 * d;
                ay = d + msyyy[k];
                d = (C1_ * (ltap<0>(Lsxy, ys, c + 1) - Lsxy[ys][c])
                   + C2_ * (ltap<0>(Lsxy, ys, c + 2) - ltap<0>(Lsxy, ys, c - 1))) * IDH_;
                msxyx[k] = bx[k] * msxyx[k] + bxm1[k] * d;
                ay = ay + d + msxyx[k];
                vy[k] = vy[k] + DT_ * bu[k] * ay;
                unsigned m = (unsigned)(sm >> (8 * k)) & 0xFFu;
                if (m) {
                    for (int js = 0; js < NSRC_; ++js)
                        if (m & (1u << js)) vy[k] += DT_ * amps[(s * NSRC_ + js) * NT_ + t] * bu[k];
                }
                vy[k] *= mk[k];
                Lvy[w - 1][c] = vy[k];
            }
        }
        if (doVx) {
            #pragma unroll
            for (int k = 0; k < 5; ++k) {
                const int c = 64 * k + lane;
                const float sxxp = (k < 4) ? sxx[k + 1] : 0.0f;
                const float sxxm = (k > 0) ? sxx[k - 1] : 0.0f;
                float d, ax;
                d = (C1_ * (sxx[k] - shtap(sxx[k], sxxm, lane, -1))
                   + C2_ * (shtap(sxx[k], sxxp, lane, 1) - shtap(sxx[k], sxxm, lane, -2))) * IDH_;
                msxxx[k] = bx[k] * msxxx[k] + bxm1[k] * d;
                ax = d + msxxx[k];
                d = (C1_ * (Lsxy[ys + 1][c] - Lsxy[ys][c]) + C2_ * (Lsxy[ys + 2][c] - Lsxy[ys - 1][c])) * IDH_;
                msxyy[k] = by * msxyy[k] + bym1 * d;
                ax = ax + d + msxyy[k];
                vx[k] = vx[k] + DT_ * bu[k] * ax;
                vx[k] *= mk[k];
                Lvx[w][c] = vx[k];
            }
        }
        __syncthreads();

        // receivers (waves 0/1 — concurrent with stress on waves 2..9)
        if (myrec) recp[t] = Lvy[rrow][rx];

        // ---- stress update (owned rows) + register-direct publish ----
        if (doS) {
            const int yv = w - 1, xv = w;
            float* Hj = H + hoff(po, s, j);
            const int slotS = (w <= 4) ? (w - 2) : (w - 4);   // valid for w in {2,3,4,7,8,9}
            #pragma unroll
            for (int k = 0; k < 5; ++k) {
                const int c = 64 * k + lane;
                float d, e1, e2, g;
                d = (C1_ * (Lvy[yv + 1][c] - vy[k]) + C2_ * (Lvy[yv + 2][c] - Lvy[yv - 1][c])) * IDH_;
                mvyy[k] = by * mvyy[k] + bym1 * d;
                e1 = d + mvyy[k];
                d = (C1_ * (vx[k] - ltap<0>(Lvx, xv, c - 1))
                   + C2_ * (ltap<0>(Lvx, xv, c + 1) - ltap<0>(Lvx, xv, c - 2))) * IDH_;
                mvxx[k] = bx[k] * mvxx[k] + bxm1[k] * d;
                e2 = d + mvxx[k];
                syy[k] = (syy[k] + DT_ * (l2m[k] * e1 + la[k] * e2)) * mk[k];
                sxx[k] = (sxx[k] + DT_ * (l2m[k] * e2 + la[k] * e1)) * mk[k];
                d = (C1_ * (ltap<0>(Lvy, yv, c + 1) - vy[k])
                   + C2_ * (ltap<0>(Lvy, yv, c + 2) - ltap<0>(Lvy, yv, c - 1))) * IDH_;
                mvyx[k] = bx[k] * mvyx[k] + bxm1[k] * d;
                g = d + mvyx[k];
                d = (C1_ * (vx[k] - Lvx[xv - 1][c]) + C2_ * (Lvx[xv + 1][c] - Lvx[xv - 2][c])) * IDH_;
                mvxy[k] = by * mvxy[k] + bym1 * d;
                g = g + d + mvxy[k];
                sxy[k] = (sxy[k] + DT_ * muv[k] * g) * mk[k];
                Lsyy[ys][c] = syy[k]; Lsxy[ys][c] = sxy[k];
                // publish halo rows straight from registers (sc1)
                if (w <= 4 || w >= 7) {
                    cst(Hj + slotS * NX_ + c, syy[k]);
                    cst(Hj + (6 + slotS) * NX_ + c, sxy[k]);
                }
                if (w == 2) cst(Hj + 12 * NX_ + c, sxx[k]);
                else if (w == 8) cst(Hj + 13 * NX_ + c, sxx[k]);
                else if (w == 9) cst(Hj + 14 * NX_ + c, sxx[k]);
            }
        }
        __syncthreads();   // compiler drains every wave's vmcnt before s_barrier
        if (tid == 0) {
            asm volatile("s_waitcnt vmcnt(0)" ::: "memory");
            cstu(&flg[sbase + j], (unsigned)(t + 1));
        }
    }

    // ---------- final output: out[s][r][t] = 0.5*(rec[t] + rec[t+1]) ----------
    if (myrec) {
        float* op = out + (s * NREC_ + tid) * (NT_ - 1);
        for (int t = 0; t < NT_ - 1; ++t) op[t] = 0.5f * (recp[t] + recp[t + 1]);
    }
}

extern "C" void kernel_launch(void* const* d_in, const int* in_sizes, int n_in,
                              void* d_out, int out_size, void* d_ws, size_t ws_size,
                              hipStream_t stream)
{
    const float* lamb = (const float*)d_in[0];
    const float* mu   = (const float*)d_in[1];
    const float* buoy = (const float*)d_in[2];
    const float* amps = (const float*)d_in[3];
    const int*   src  = (const int*)d_in[4];
    const int*   recl = (const int*)d_in[5];
    float* out = (float*)d_out;
    float* ws  = (float*)d_ws;

    init_kernel<<<dim3(512), dim3(256), 0, stream>>>(ws);
    elastic_kernel<<<dim3(NBLK_), dim3(768), 0, stream>>>(lamb, mu, buoy, amps, src, recl, out, ws);
}

// Round 8
// 1918.193 us; speedup vs baseline: 1.0087x; 1.0087x over previous
//
#include <hip/hip_runtime.h>
#include <math.h>

constexpr int NY_ = 320, NX_ = 320, NT_ = 160, SHOTS_ = 2, NSRC_ = 8, NREC_ = 96;
constexpr float DT_  = 4.0e-4f;
constexpr float C1_  = 9.0f / 8.0f;
constexpr float C2_  = -1.0f / 24.0f;
constexpr float IDH_ = 0.25f;           // 1/DH, exact
constexpr int NSTRIP_ = 40;             // 8-row strips per shot
constexpr int NBLK_   = SHOTS_ * NSTRIP_;
// Compact publish slots: per (parity, shot, strip) 15 rows x 320:
//   slots 0-2: syy rows r0,r0+1,r0+2   slots 3-5: syy rows r0+5,r0+6,r0+7
//   slots 6-8: sxy rows r0..r0+2       slots 9-11: sxy rows r0+5..r0+7
//   slot 12: sxx row r0                slots 13,14: sxx rows r0+6,r0+7
constexpr int HSLOT_   = 15 * NX_;
constexpr int REC_OFF_ = 2 * SHOTS_ * NSTRIP_ * HSLOT_;        // 768000 floats
constexpr int FLG_OFF_ = REC_OFF_ + SHOTS_ * NREC_ * NT_;      // +30720
constexpr int WS_WORDS_ = FLG_OFF_ + 256;

__device__ __forceinline__ int hoff(int p, int s, int j) {
    return ((p * SHOTS_ + s) * NSTRIP_ + j) * HSLOT_;
}

// ---- coherent (IF-backed) access: relaxed agent-scope atomics -> sc0 sc1,
// bypass L1/L2, served at the agent coherence point. No cache flushes needed.
__device__ __forceinline__ float cld(const float* p) {
    return __hip_atomic_load(p, __ATOMIC_RELAXED, __HIP_MEMORY_SCOPE_AGENT);
}
__device__ __forceinline__ void cst(float* p, float v) {
    __hip_atomic_store(p, v, __ATOMIC_RELAXED, __HIP_MEMORY_SCOPE_AGENT);
}
__device__ __forceinline__ unsigned cldu(const unsigned* p) {
    return __hip_atomic_load(p, __ATOMIC_RELAXED, __HIP_MEMORY_SCOPE_AGENT);
}
__device__ __forceinline__ void cstu(unsigned* p, unsigned v) {
    __hip_atomic_store(p, v, __ATOMIC_RELAXED, __HIP_MEMORY_SCOPE_AGENT);
}

// guarded LDS x-tap: out-of-grid cols read 0 (jnp.roll-wrap lands in the
// 2-wide masked-zero border -> exactly equivalent; verified rounds 2-7)
template <int R>
__device__ __forceinline__ float ltap(const float (*A)[NX_], int ly, int c) {
    return ((unsigned)c < (unsigned)NX_) ? A[ly][c] : 0.0f;
}
// register x-tap via wave shuffle (cells 64-col interleaved per thread)
__device__ __forceinline__ float shtap(float cur, float adj, int lane, int dx) {
    int idx = (lane + dx) & 63;
    float a = __shfl(cur, idx, 64);
    float b = __shfl(adj, idx, 64);
    return ((unsigned)(lane + dx) < 64u) ? a : b;
}

// P2P neighbor sync (round-5/6-verified pattern): wave 0 polls j+/-1 flags.
__device__ __forceinline__ void pollNbr(const unsigned* f, int sbase, int j,
                                        unsigned tgt, int tid) {
    __syncthreads();
    if (tid < 64) {
        for (;;) {
            bool ok = true;
            if (tid == 0 && j > 0)                ok = cldu(&f[sbase + j - 1]) >= tgt;
            else if (tid == 1 && j < NSTRIP_ - 1) ok = cldu(&f[sbase + j + 1]) >= tgt;
            if (__all(ok)) break;
            __builtin_amdgcn_s_sleep(1);
        }
    }
    __syncthreads();
    asm volatile("" ::: "memory");
}

__global__ void init_kernel(float* __restrict__ ws) {
    for (int i = blockIdx.x * 256 + threadIdx.x; i < WS_WORDS_; i += gridDim.x * 256)
        ws[i] = 0.0f;
}

// __launch_bounds__(768, 3): 3 waves/EU = ONE 12-wave block per CU.
// Round-7 post-mortem: without the 2nd arg the compiler targeted 2 blocks/CU
// and capped VGPRs at 84 (< ~100 floats of persistent CPML state) -> scratch
// spills in the K-loop. 80 blocks on 256 CUs never need 2 blocks/CU.
__global__ __launch_bounds__(768, 3)
void elastic_kernel(const float* __restrict__ lamb, const float* __restrict__ mu,
                    const float* __restrict__ buoy, const float* __restrict__ amps,
                    const int* __restrict__ src_loc, const int* __restrict__ rec_loc,
                    float* __restrict__ out, float* __restrict__ ws)
{
    // Extended stress region rows [r0-3, r0+10] -> LDS rows 0..13.
    // Velocity: vy rows [r0-1, r0+9] -> Lvy 0..10; vx rows [r0-2, r0+8] -> Lvx 0..10.
    __shared__ float Lsyy[14][NX_], Lsxy[14][NX_], Lvy[11][NX_], Lvx[11][NX_];

    const int tid  = threadIdx.x;
    const int lane = tid & 63;
    const int w    = tid >> 6;          // wave = row index, 12 waves
    const int bid  = blockIdx.x;
    const int s    = bid / NSTRIP_;
    const int j    = bid % NSTRIP_;
    const int r0   = j * 8;
    const int gy   = r0 - 2 + w;        // this wave's global row (r0-2 .. r0+9)
    const int ys   = w + 1;             // stress LDS row for gy
    const bool doVy = (w >= 1);         // vy computed on rows r0-1..r0+9
    const bool doVx = (w <= 10);        // vx computed on rows r0-2..r0+8
    const bool doS  = (w >= 2 && w <= 9);  // stress on owned rows r0..r0+7

    float* H = ws;                                   // publish slots
    float* recp = ws + REC_OFF_ + (s * NREC_ + tid) * NT_;   // valid if tid<96
    unsigned* flg = (unsigned*)(ws + FLG_OFF_);
    const int sbase = s * NSTRIP_;

    // --- loop invariants (double-precision PML to match numpy) ---
    const double d0 = 3.0 * 1600.0 * log(1000.0) / (2.0 * 20.0 * 4.0);
    double py = 0.0;
    if (gy < 20)             { double u = (20.0 - gy) / 20.0;           py = u * u; }
    else if (gy >= NY_ - 20) { double u = (gy - (NY_ - 1 - 20)) / 20.0; py = u * u; }
    const float by = (float)exp(-d0 * py * 4.0e-4);
    const float bym1 = by - 1.0f;
    const int gyc = gy < 0 ? 0 : (gy > NY_ - 1 ? NY_ - 1 : gy);   // clamp for material loads

    float bx[5], bxm1[5], mk[5], la[5], muv[5], bu[5], l2m[5];
    #pragma unroll
    for (int k = 0; k < 5; ++k) {
        int c = 64 * k + lane;
        double px = 0.0;
        if (c < 20)             { double u = (20.0 - c) / 20.0;           px = u * u; }
        else if (c >= NX_ - 20) { double u = (c - (NX_ - 1 - 20)) / 20.0; px = u * u; }
        bx[k] = (float)exp(-d0 * px * 4.0e-4);
        bxm1[k] = bx[k] - 1.0f;
        mk[k] = (gy < 2 || gy >= NY_ - 2 || c < 2 || c >= NX_ - 2) ? 0.0f : 1.0f;
        la[k]  = lamb[gyc * NX_ + c];
        muv[k] = mu[gyc * NX_ + c];
        bu[k]  = buoy[gyc * NX_ + c];
        l2m[k] = la[k] + 2.0f * muv[k];
    }

    // source mask (halo rows included -> redundancy-consistent injection)
    unsigned long long sm = 0ull;
    for (int js = 0; js < NSRC_; ++js) {
        int sy = src_loc[(s * NSRC_ + js) * 2 + 0];
        int sx = src_loc[(s * NSRC_ + js) * 2 + 1];
        if (sy == gy && (sx & 63) == lane) sm |= 1ull << (8 * (sx >> 6) + js);
    }
    bool myrec = false; int rrow = 0, rx = 0;
    if (tid < NREC_) {
        int ry = rec_loc[(s * NREC_ + tid) * 2 + 0];
        rx     = rec_loc[(s * NREC_ + tid) * 2 + 1];
        if ((ry >> 3) == j) { myrec = true; rrow = ry - r0 + 1; }   // Lvy row
    }

    // zero LDS (boundary-strip halo rows rely on these zeros persisting)
    for (int i = tid; i < 14 * NX_; i += 768) { ((float*)Lsyy)[i] = 0.f; ((float*)Lsxy)[i] = 0.f; }
    for (int i = tid; i < 11 * NX_; i += 768) { ((float*)Lvy)[i] = 0.f; ((float*)Lvx)[i] = 0.f; }

    // register state for this wave's row
    float vy[5] = {}, vx[5] = {}, syy[5] = {}, sxy[5] = {}, sxx[5] = {};
    float msyyy[5] = {}, msxyy[5] = {}, msxyx[5] = {}, msxxx[5] = {};
    float mvyy[5] = {}, mvyx[5] = {}, mvxy[5] = {}, mvxx[5] = {};

    for (int t = 0; t < NT_; ++t) {
        // ---- one sync point per timestep: neighbors' stress(t-1) published ----
        pollNbr(flg, sbase, j, (unsigned)t, tid);
        const int pi = (t + 1) & 1;     // import parity ((t-1)&1)
        const int po = t & 1;           // publish parity

        // import stress halos into LDS (12 rows) -- zeros persist at grid edges
        if (tid < NX_) {
            int c = tid;
            if (j > 0) {
                const float* b = H + hoff(pi, s, j - 1);
                float a0 = cld(b + 3 * NX_ + c), a1 = cld(b + 4 * NX_ + c), a2 = cld(b + 5 * NX_ + c);
                float d0_ = cld(b + 9 * NX_ + c), d1 = cld(b + 10 * NX_ + c), d2 = cld(b + 11 * NX_ + c);
                Lsyy[0][c] = a0; Lsyy[1][c] = a1; Lsyy[2][c] = a2;
                Lsxy[0][c] = d0_; Lsxy[1][c] = d1; Lsxy[2][c] = d2;
            }
            if (j < NSTRIP_ - 1) {
                const float* b = H + hoff(pi, s, j + 1);
                float a0 = cld(b + 0 * NX_ + c), a1 = cld(b + 1 * NX_ + c), a2 = cld(b + 2 * NX_ + c);
                float d0_ = cld(b + 6 * NX_ + c), d1 = cld(b + 7 * NX_ + c), d2 = cld(b + 8 * NX_ + c);
                Lsyy[11][c] = a0; Lsyy[12][c] = a1; Lsyy[13][c] = a2;
                Lsxy[11][c] = d0_; Lsxy[12][c] = d1; Lsxy[13][c] = d2;
            }
        }
        // sxx register import for halo waves (rows r0-2, r0-1, r0+8)
        if (w == 0 && j > 0) {
            const float* b = H + hoff(pi, s, j - 1) + 13 * NX_;
            #pragma unroll
            for (int k = 0; k < 5; ++k) sxx[k] = cld(b + 64 * k + lane);
        } else if (w == 1 && j > 0) {
            const float* b = H + hoff(pi, s, j - 1) + 14 * NX_;
            #pragma unroll
            for (int k = 0; k < 5; ++k) sxx[k] = cld(b + 64 * k + lane);
        } else if (w == 10 && j < NSTRIP_ - 1) {
            const float* b = H + hoff(pi, s, j + 1) + 12 * NX_;
            #pragma unroll
            for (int k = 0; k < 5; ++k) sxx[k] = cld(b + 64 * k + lane);
        }
        __syncthreads();

        // ---- velocity update (owned + redundant halo rows) ----
        if (doVy) {
            #pragma unroll
            for (int k = 0; k < 5; ++k) {
                const int c = 64 * k + lane;
                float d, ay;
                d = (C1_ * (Lsyy[ys][c] - Lsyy[ys - 1][c]) + C2_ * (Lsyy[ys + 1][c] - Lsyy[ys - 2][c])) * IDH_;
                msyyy[k] = by * msyyy[k] + bym1 * d;
                ay = d + msyyy[k];
                d = (C1_ * (ltap<0>(Lsxy, ys, c + 1) - Lsxy[ys][c])
                   + C2_ * (ltap<0>(Lsxy, ys, c + 2) - ltap<0>(Lsxy, ys, c - 1))) * IDH_;
                msxyx[k] = bx[k] * msxyx[k] + bxm1[k] * d;
                ay = ay + d + msxyx[k];
                vy[k] = vy[k] + DT_ * bu[k] * ay;
                unsigned m = (unsigned)(sm >> (8 * k)) & 0xFFu;
                if (m) {
                    for (int js = 0; js < NSRC_; ++js)
                        if (m & (1u << js)) vy[k] += DT_ * amps[(s * NSRC_ + js) * NT_ + t] * bu[k];
                }
                vy[k] *= mk[k];
                Lvy[w - 1][c] = vy[k];
            }
        }
        if (doVx) {
            #pragma unroll
            for (int k = 0; k < 5; ++k) {
                const int c = 64 * k + lane;
                const float sxxp = (k < 4) ? sxx[k + 1] : 0.0f;
                const float sxxm = (k > 0) ? sxx[k - 1] : 0.0f;
                float d, ax;
                d = (C1_ * (sxx[k] - shtap(sxx[k], sxxm, lane, -1))
                   + C2_ * (shtap(sxx[k], sxxp, lane, 1) - shtap(sxx[k], sxxm, lane, -2))) * IDH_;
                msxxx[k] = bx[k] * msxxx[k] + bxm1[k] * d;
                ax = d + msxxx[k];
                d = (C1_ * (Lsxy[ys + 1][c] - Lsxy[ys][c]) + C2_ * (Lsxy[ys + 2][c] - Lsxy[ys - 1][c])) * IDH_;
                msxyy[k] = by * msxyy[k] + bym1 * d;
                ax = ax + d + msxyy[k];
                vx[k] = vx[k] + DT_ * bu[k] * ax;
                vx[k] *= mk[k];
                Lvx[w][c] = vx[k];
            }
        }
        __syncthreads();

        // receivers (waves 0/1 — concurrent with stress on waves 2..9)
        if (myrec) recp[t] = Lvy[rrow][rx];

        // ---- stress update (owned rows) + register-direct publish ----
        if (doS) {
            const int yv = w - 1, xv = w;
            float* Hj = H + hoff(po, s, j);
            const int slotS = (w <= 4) ? (w - 2) : (w - 4);   // valid for w in {2,3,4,7,8,9}
            #pragma unroll
            for (int k = 0; k < 5; ++k) {
                const int c = 64 * k + lane;
                float d, e1, e2, g;
                d = (C1_ * (Lvy[yv + 1][c] - vy[k]) + C2_ * (Lvy[yv + 2][c] - Lvy[yv - 1][c])) * IDH_;
                mvyy[k] = by * mvyy[k] + bym1 * d;
                e1 = d + mvyy[k];
                d = (C1_ * (vx[k] - ltap<0>(Lvx, xv, c - 1))
                   + C2_ * (ltap<0>(Lvx, xv, c + 1) - ltap<0>(Lvx, xv, c - 2))) * IDH_;
                mvxx[k] = bx[k] * mvxx[k] + bxm1[k] * d;
                e2 = d + mvxx[k];
                syy[k] = (syy[k] + DT_ * (l2m[k] * e1 + la[k] * e2)) * mk[k];
                sxx[k] = (sxx[k] + DT_ * (l2m[k] * e2 + la[k] * e1)) * mk[k];
                d = (C1_ * (ltap<0>(Lvy, yv, c + 1) - vy[k])
                   + C2_ * (ltap<0>(Lvy, yv, c + 2) - ltap<0>(Lvy, yv, c - 1))) * IDH_;
                mvyx[k] = bx[k] * mvyx[k] + bxm1[k] * d;
                g = d + mvyx[k];
                d = (C1_ * (vx[k] - Lvx[xv - 1][c]) + C2_ * (Lvx[xv + 1][c] - Lvx[xv - 2][c])) * IDH_;
                mvxy[k] = by * mvxy[k] + bym1 * d;
                g = g + d + mvxy[k];
                sxy[k] = (sxy[k] + DT_ * muv[k] * g) * mk[k];
                Lsyy[ys][c] = syy[k]; Lsxy[ys][c] = sxy[k];
                // publish halo rows straight from registers (sc1)
                if (w <= 4 || w >= 7) {
                    cst(Hj + slotS * NX_ + c, syy[k]);
                    cst(Hj + (6 + slotS) * NX_ + c, sxy[k]);
                }
                if (w == 2) cst(Hj + 12 * NX_ + c, sxx[k]);
                else if (w == 8) cst(Hj + 13 * NX_ + c, sxx[k]);
                else if (w == 9) cst(Hj + 14 * NX_ + c, sxx[k]);
            }
        }
        __syncthreads();   // compiler drains every wave's vmcnt before s_barrier
        if (tid == 0) {
            asm volatile("s_waitcnt vmcnt(0)" ::: "memory");
            cstu(&flg[sbase + j], (unsigned)(t + 1));
        }
    }

    // ---------- final output: out[s][r][t] = 0.5*(rec[t] + rec[t+1]) ----------
    if (myrec) {
        float* op = out + (s * NREC_ + tid) * (NT_ - 1);
        for (int t = 0; t < NT_ - 1; ++t) op[t] = 0.5f * (recp[t] + recp[t + 1]);
    }
}

extern "C" void kernel_launch(void* const* d_in, const int* in_sizes, int n_in,
                              void* d_out, int out_size, void* d_ws, size_t ws_size,
                              hipStream_t stream)
{
    const float* lamb = (const float*)d_in[0];
    const float* mu   = (const float*)d_in[1];
    const float* buoy = (const float*)d_in[2];
    const float* amps = (const float*)d_in[3];
    const int*   src  = (const int*)d_in[4];
    const int*   recl = (const int*)d_in[5];
    float* out = (float*)d_out;
    float* ws  = (float*)d_ws;

    init_kernel<<<dim3(512), dim3(256), 0, stream>>>(ws);
    elastic_kernel<<<dim3(NBLK_), dim3(768), 0, stream>>>(lamb, mu, buoy, amps, src, recl, out, ws);
}

// Round 9
// 1474.516 us; speedup vs baseline: 1.3122x; 1.3009x over previous
//
#include <hip/hip_runtime.h>
#include <math.h>

constexpr int NY_ = 320, NX_ = 320, NT_ = 160, SHOTS_ = 2, NSRC_ = 8, NREC_ = 96;
constexpr float DT_  = 4.0e-4f;
constexpr float C1_  = 9.0f / 8.0f;
constexpr float C2_  = -1.0f / 24.0f;
constexpr float IDH_ = 0.25f;           // 1/DH, exact
constexpr int NSTRIP_ = 40;             // 8-row strips per shot
constexpr int NBLK_   = SHOTS_ * NSTRIP_;
// Publish slots, per (parity, shot, strip), 6 rows x 320 each:
//  vel slot:    [0]=vy r0   [1]=vx r0   [2]=vy r0+1 [3]=vx r0+6 [4]=vy r0+7 [5]=vx r0+7
//  stress slot: [0]=syy r0  [1]=sxy r0  [2]=sxy r0+1 [3]=syy r0+6 [4]=syy r0+7 [5]=sxy r0+7
constexpr int SLOT_    = 6 * NX_;
constexpr int VS_OFF_  = 0;
constexpr int SS_OFF_  = VS_OFF_ + 2 * SHOTS_ * NSTRIP_ * SLOT_;   // 307200
constexpr int REC_OFF_ = SS_OFF_ + 2 * SHOTS_ * NSTRIP_ * SLOT_;   // 614400
constexpr int GF_OFF_  = REC_OFF_ + SHOTS_ * NREC_ * NT_;          // +30720
constexpr int WS_WORDS_ = GF_OFF_ + 8 * NBLK_ + 64;

// ---- coherent (IF-backed) access: relaxed agent-scope atomics -> sc0 sc1,
// bypass L1/L2, served at the agent coherence point (verified r3-r8).
__device__ __forceinline__ float cld(const float* p) {
    return __hip_atomic_load(p, __ATOMIC_RELAXED, __HIP_MEMORY_SCOPE_AGENT);
}
__device__ __forceinline__ void cst(float* p, float v) {
    __hip_atomic_store(p, v, __ATOMIC_RELAXED, __HIP_MEMORY_SCOPE_AGENT);
}
__device__ __forceinline__ unsigned cldu(const unsigned* p) {
    return __hip_atomic_load(p, __ATOMIC_RELAXED, __HIP_MEMORY_SCOPE_AGENT);
}
__device__ __forceinline__ void cstu(unsigned* p, unsigned v) {
    __hip_atomic_store(p, v, __ATOMIC_RELAXED, __HIP_MEMORY_SCOPE_AGENT);
}
// ---- LDS progress flags: workgroup-scope acquire/release counters.
__device__ __forceinline__ void lwait(const unsigned* f, unsigned tgt) {
    while (__hip_atomic_load(f, __ATOMIC_ACQUIRE, __HIP_MEMORY_SCOPE_WORKGROUP) < tgt) {}
}
__device__ __forceinline__ void lpost(unsigned* f, unsigned v) {
    __hip_atomic_store(f, v, __ATOMIC_RELEASE, __HIP_MEMORY_SCOPE_WORKGROUP);
}
// global 2-flag poll (edge waves only)
__device__ __forceinline__ void gwait2(const unsigned* a, const unsigned* b, unsigned tgt) {
    while (cldu(a) < tgt || cldu(b) < tgt) __builtin_amdgcn_s_sleep(1);
    asm volatile("" ::: "memory");
}
// register x-tap via wave shuffle (verified r5-r8)
__device__ __forceinline__ float shtap(float cur, float adj, int lane, int dx) {
    int idx = (lane + dx) & 63;
    float a = __shfl(cur, idx, 64);
    float b = __shfl(adj, idx, 64);
    return ((unsigned)(lane + dx) < 64u) ? a : b;
}

__global__ void init_kernel(float* __restrict__ ws) {
    for (int i = blockIdx.x * 256 + threadIdx.x; i < WS_WORDS_; i += gridDim.x * 256)
        ws[i] = 0.0f;
}

__global__ __launch_bounds__(512, 2)
void elastic_kernel(const float* __restrict__ lamb, const float* __restrict__ mu,
                    const float* __restrict__ buoy, const float* __restrict__ amps,
                    const int* __restrict__ src_loc, const int* __restrict__ rec_loc,
                    float* __restrict__ out, float* __restrict__ ws)
{
    // LDS row index = gy - r0 + 2: halo rows {0,1,10,11}, own rows 2..9.
    __shared__ float Lsyy[12][NX_], Lsxy[12][NX_], Lvy[12][NX_], Lvx[12][NX_];
    __shared__ unsigned vF[8], sF[8], hF[4];   // hF: 0=hsB 1=hsT 2=hvB 3=hvT

    const int tid = threadIdx.x, lane = tid & 63, w = tid >> 6;
    const int bid = blockIdx.x, s = bid / NSTRIP_, j = bid % NSTRIP_;
    const int r0 = j * 8, gy = r0 + w, yi = w + 2;
    const int sj = s * NSTRIP_ + j;
    unsigned* gV = (unsigned*)(ws + GF_OFF_);          // [role(4)][NBLK_]
    unsigned* gS = gV + 4 * NBLK_;

    // --- loop invariants (double PML, matches numpy; verified r2-r8) ---
    const double d0 = 3.0 * 1600.0 * log(1000.0) / (2.0 * 20.0 * 4.0);
    double py = 0.0;
    if (gy < 20)             { double u = (20.0 - gy) / 20.0;           py = u * u; }
    else if (gy >= NY_ - 20) { double u = (gy - (NY_ - 1 - 20)) / 20.0; py = u * u; }
    const float by = (float)exp(-d0 * py * 4.0e-4);
    const float bym1 = by - 1.0f;

    float bx[5], bxm1[5], mk[5], la[5], muv[5], bu[5], l2m[5];
    #pragma unroll
    for (int k = 0; k < 5; ++k) {
        int c = 64 * k + lane;
        double px = 0.0;
        if (c < 20)             { double u = (20.0 - c) / 20.0;           px = u * u; }
        else if (c >= NX_ - 20) { double u = (c - (NX_ - 1 - 20)) / 20.0; px = u * u; }
        bx[k] = (float)exp(-d0 * px * 4.0e-4);
        bxm1[k] = bx[k] - 1.0f;
        mk[k] = (gy < 2 || gy >= NY_ - 2 || c < 2 || c >= NX_ - 2) ? 0.0f : 1.0f;
        la[k]  = lamb[gy * NX_ + c];
        muv[k] = mu[gy * NX_ + c];
        bu[k]  = buoy[gy * NX_ + c];
        l2m[k] = la[k] + 2.0f * muv[k];
    }
    // per-thread sources
    unsigned long long sm = 0ull;
    for (int js = 0; js < NSRC_; ++js) {
        int sy = src_loc[(s * NSRC_ + js) * 2 + 0];
        int sx = src_loc[(s * NSRC_ + js) * 2 + 1];
        if (sy == gy && (sx & 63) == lane) sm |= 1ull << (8 * (sx >> 6) + js);
    }
    // per-thread receiver ownership: the owning thread records its own register.
    int nrec = 0, recid[8], reck[8];
    for (int r = 0; r < NREC_; ++r) {
        int ry = rec_loc[(s * NREC_ + r) * 2 + 0];
        int rx = rec_loc[(s * NREC_ + r) * 2 + 1];
        if (ry == gy && (rx & 63) == lane && nrec < 8) { recid[nrec] = r; reck[nrec] = rx >> 6; ++nrec; }
    }
    float* recbase = ws + REC_OFF_;

    for (int i = tid; i < 12 * NX_; i += 512) {
        ((float*)Lsyy)[i] = 0.f; ((float*)Lsxy)[i] = 0.f;
        ((float*)Lvy)[i]  = 0.f; ((float*)Lvx)[i]  = 0.f;
    }
    if (tid < 8) { vF[tid] = 0u; sF[tid] = 0u; }
    if (tid < 4) hF[tid] = 0u;
    __syncthreads();   // the only block barrier in the kernel

    float vy[5] = {}, vx[5] = {}, syy[5] = {}, sxy[5] = {}, sxx[5] = {};
    float msyyy[5] = {}, msxyy[5] = {}, msxyx[5] = {}, msxxx[5] = {};
    float mvyy[5] = {}, mvyx[5] = {}, mvxy[5] = {}, mvxx[5] = {};

    for (int t = 0; t < NT_; ++t) {
        const unsigned ut = (unsigned)t;
        const int pi = (t + 1) & 1, po = t & 1;   // import / publish parity

        // ================= VELOCITY(t) =================
        if (w == 0) {                 // bottom stress-halo import
            if (j > 0) {
                lwait(&vF[1], ut);    // WAR: wave1's vel(t-1) read of Lsyy[1] done
                gwait2(&gS[2 * NBLK_ + (sj - 1)], &gS[3 * NBLK_ + (sj - 1)], ut);
                const float* B = ws + SS_OFF_ + ((pi * SHOTS_ + s) * NSTRIP_ + (j - 1)) * SLOT_;
                #pragma unroll
                for (int k = 0; k < 5; ++k) {
                    int c = 64 * k + lane;
                    float a = cld(B + 3 * NX_ + c), b = cld(B + 4 * NX_ + c), e = cld(B + 5 * NX_ + c);
                    Lsyy[0][c] = a; Lsyy[1][c] = b; Lsxy[1][c] = e;
                }
            }
            lpost(&hF[0], ut + 1u);
        } else if (w == 7) {          // top stress-halo import
            if (j < NSTRIP_ - 1) {
                lwait(&vF[6], ut);    // WAR: wave6's vel(t-1) read of Lsxy[10] done
                gwait2(&gS[0 * NBLK_ + (sj + 1)], &gS[1 * NBLK_ + (sj + 1)], ut);
                const float* B = ws + SS_OFF_ + ((pi * SHOTS_ + s) * NSTRIP_ + (j + 1)) * SLOT_;
                #pragma unroll
                for (int k = 0; k < 5; ++k) {
                    int c = 64 * k + lane;
                    float a = cld(B + 0 * NX_ + c), b = cld(B + 1 * NX_ + c), e = cld(B + 2 * NX_ + c);
                    Lsyy[10][c] = a; Lsxy[10][c] = b; Lsxy[11][c] = e;
                }
            }
            lpost(&hF[1], ut + 1u);
        }
        if (w == 1) lwait(&hF[0], ut + 1u);
        if (w == 6) lwait(&hF[1], ut + 1u);
        if (w >= 2) lwait(&sF[w - 2], ut);
        if (w >= 1) lwait(&sF[w - 1], ut);
        if (w <= 6) lwait(&sF[w + 1], ut);
        if (w <= 5) lwait(&sF[w + 2], ut);

        #pragma unroll
        for (int k = 0; k < 5; ++k) {
            const int c = 64 * k + lane;
            const float sxyP = (k < 4) ? sxy[k + 1] : 0.0f;
            const float sxyM = (k > 0) ? sxy[k - 1] : 0.0f;
            const float sxxP = (k < 4) ? sxx[k + 1] : 0.0f;
            const float sxxM = (k > 0) ? sxx[k - 1] : 0.0f;
            float d, ay, ax;
            d = (C1_ * (syy[k] - Lsyy[yi - 1][c]) + C2_ * (Lsyy[yi + 1][c] - Lsyy[yi - 2][c])) * IDH_;
            msyyy[k] = by * msyyy[k] + bym1 * d;
            ay = d + msyyy[k];
            d = (C1_ * (shtap(sxy[k], sxyP, lane, 1) - sxy[k])
               + C2_ * (shtap(sxy[k], sxyP, lane, 2) - shtap(sxy[k], sxyM, lane, -1))) * IDH_;
            msxyx[k] = bx[k] * msxyx[k] + bxm1[k] * d;
            ay = ay + d + msxyx[k];
            vy[k] = vy[k] + DT_ * bu[k] * ay;
            d = (C1_ * (sxx[k] - shtap(sxx[k], sxxM, lane, -1))
               + C2_ * (shtap(sxx[k], sxxP, lane, 1) - shtap(sxx[k], sxxM, lane, -2))) * IDH_;
            msxxx[k] = bx[k] * msxxx[k] + bxm1[k] * d;
            ax = d + msxxx[k];
            d = (C1_ * (Lsxy[yi + 1][c] - sxy[k]) + C2_ * (Lsxy[yi + 2][c] - Lsxy[yi - 1][c])) * IDH_;
            msxyy[k] = by * msxyy[k] + bym1 * d;
            ax = ax + d + msxyy[k];
            vx[k] = vx[k] + DT_ * bu[k] * ax;
            unsigned m = (unsigned)(sm >> (8 * k)) & 0xFFu;
            if (m) {
                for (int js = 0; js < NSRC_; ++js)
                    if (m & (1u << js)) vy[k] += DT_ * amps[(s * NSRC_ + js) * NT_ + t] * bu[k];
            }
            vy[k] *= mk[k]; vx[k] *= mk[k];
            Lvy[yi][c] = vy[k]; Lvx[yi][c] = vx[k];
        }
        lpost(&vF[w], ut + 1u);
        for (int i = 0; i < nrec; ++i)   // record own register (plain store, same-thread RW)
            recbase[(s * NREC_ + recid[i]) * NT_ + t] = vy[reck[i]];

        if (w == 0 || w == 1 || w == 6 || w == 7) {   // publish velocity halo rows
            float* P = ws + VS_OFF_ + ((po * SHOTS_ + s) * NSTRIP_ + j) * SLOT_;
            #pragma unroll
            for (int k = 0; k < 5; ++k) {
                int c = 64 * k + lane;
                if (w == 0) { cst(P + 0 * NX_ + c, vy[k]); cst(P + 1 * NX_ + c, vx[k]); }
                else if (w == 1) cst(P + 2 * NX_ + c, vy[k]);
                else if (w == 6) cst(P + 3 * NX_ + c, vx[k]);
                else { cst(P + 4 * NX_ + c, vy[k]); cst(P + 5 * NX_ + c, vx[k]); }
            }
            asm volatile("s_waitcnt vmcnt(0)" ::: "memory");
            const int role = (w == 0) ? 0 : (w == 1) ? 1 : (w == 6) ? 2 : 3;
            cstu(&gV[role * NBLK_ + sj], ut + 1u);
        }

        // ================= STRESS(t) =================
        if (w == 0) {                 // bottom velocity-halo import
            if (j > 0) {
                lwait(&sF[1], ut);    // WAR: wave1's stress(t-1) read of Lvx[1] done
                gwait2(&gV[2 * NBLK_ + (sj - 1)], &gV[3 * NBLK_ + (sj - 1)], ut + 1u);
                const float* B = ws + VS_OFF_ + ((po * SHOTS_ + s) * NSTRIP_ + (j - 1)) * SLOT_;
                #pragma unroll
                for (int k = 0; k < 5; ++k) {
                    int c = 64 * k + lane;
                    float a = cld(B + 3 * NX_ + c), b = cld(B + 4 * NX_ + c), e = cld(B + 5 * NX_ + c);
                    Lvx[0][c] = a; Lvy[1][c] = b; Lvx[1][c] = e;
                }
            }
            lpost(&hF[2], ut + 1u);
        } else if (w == 7) {          // top velocity-halo import
            if (j < NSTRIP_ - 1) {
                lwait(&sF[6], ut);    // WAR: wave6's stress(t-1) read of Lvy[10] done
                gwait2(&gV[0 * NBLK_ + (sj + 1)], &gV[1 * NBLK_ + (sj + 1)], ut + 1u);
                const float* B = ws + VS_OFF_ + ((po * SHOTS_ + s) * NSTRIP_ + (j + 1)) * SLOT_;
                #pragma unroll
                for (int k = 0; k < 5; ++k) {
                    int c = 64 * k + lane;
                    float a = cld(B + 0 * NX_ + c), b = cld(B + 1 * NX_ + c), e = cld(B + 2 * NX_ + c);
                    Lvy[10][c] = a; Lvx[10][c] = b; Lvy[11][c] = e;
                }
            }
            lpost(&hF[3], ut + 1u);
        }
        if (w == 1) lwait(&hF[2], ut + 1u);
        if (w == 6) lwait(&hF[3], ut + 1u);
        if (w >= 2) lwait(&vF[w - 2], ut + 1u);
        if (w >= 1) lwait(&vF[w - 1], ut + 1u);
        if (w <= 6) lwait(&vF[w + 1], ut + 1u);
        if (w <= 5) lwait(&vF[w + 2], ut + 1u);

        #pragma unroll
        for (int k = 0; k < 5; ++k) {
            const int c = 64 * k + lane;
            const float vyP = (k < 4) ? vy[k + 1] : 0.0f;
            const float vyM = (k > 0) ? vy[k - 1] : 0.0f;
            const float vxP = (k < 4) ? vx[k + 1] : 0.0f;
            const float vxM = (k > 0) ? vx[k - 1] : 0.0f;
            float d, e1, e2, g;
            d = (C1_ * (Lvy[yi + 1][c] - vy[k]) + C2_ * (Lvy[yi + 2][c] - Lvy[yi - 1][c])) * IDH_;
            mvyy[k] = by * mvyy[k] + bym1 * d;
            e1 = d + mvyy[k];
            d = (C1_ * (vx[k] - shtap(vx[k], vxM, lane, -1))
               + C2_ * (shtap(vx[k], vxP, lane, 1) - shtap(vx[k], vxM, lane, -2))) * IDH_;
            mvxx[k] = bx[k] * mvxx[k] + bxm1[k] * d;
            e2 = d + mvxx[k];
            syy[k] = (syy[k] + DT_ * (l2m[k] * e1 + la[k] * e2)) * mk[k];
            sxx[k] = (sxx[k] + DT_ * (l2m[k] * e2 + la[k] * e1)) * mk[k];
            d = (C1_ * (shtap(vy[k], vyP, lane, 1) - vy[k])
               + C2_ * (shtap(vy[k], vyP, lane, 2) - shtap(vy[k], vyM, lane, -1))) * IDH_;
            mvyx[k] = bx[k] * mvyx[k] + bxm1[k] * d;
            g = d + mvyx[k];
            d = (C1_ * (vx[k] - Lvx[yi - 1][c]) + C2_ * (Lvx[yi + 1][c] - Lvx[yi - 2][c])) * IDH_;
            mvxy[k] = by * mvxy[k] + bym1 * d;
            g = g + d + mvxy[k];
            sxy[k] = (sxy[k] + DT_ * muv[k] * g) * mk[k];
            Lsyy[yi][c] = syy[k]; Lsxy[yi][c] = sxy[k];
        }
        lpost(&sF[w], ut + 1u);

        if (w == 0 || w == 1 || w == 6 || w == 7) {   // publish stress halo rows
            float* P = ws + SS_OFF_ + ((po * SHOTS_ + s) * NSTRIP_ + j) * SLOT_;
            #pragma unroll
            for (int k = 0; k < 5; ++k) {
                int c = 64 * k + lane;
                if (w == 0) { cst(P + 0 * NX_ + c, syy[k]); cst(P + 1 * NX_ + c, sxy[k]); }
                else if (w == 1) cst(P + 2 * NX_ + c, sxy[k]);
                else if (w == 6) cst(P + 3 * NX_ + c, syy[k]);
                else { cst(P + 4 * NX_ + c, syy[k]); cst(P + 5 * NX_ + c, sxy[k]); }
            }
            asm volatile("s_waitcnt vmcnt(0)" ::: "memory");
            const int role = (w == 0) ? 0 : (w == 1) ? 1 : (w == 6) ? 2 : 3;
            cstu(&gS[role * NBLK_ + sj], ut + 1u);
        }
    }

    // ---------- final output: out[s][r][t] = 0.5*(rec[t] + rec[t+1]) ----------
    for (int i = 0; i < nrec; ++i) {
        const float* rp = recbase + (s * NREC_ + recid[i]) * NT_;
        float* op = out + (s * NREC_ + recid[i]) * (NT_ - 1);
        for (int t = 0; t < NT_ - 1; ++t) op[t] = 0.5f * (rp[t] + rp[t + 1]);
    }
}

extern "C" void kernel_launch(void* const* d_in, const int* in_sizes, int n_in,
                              void* d_out, int out_size, void* d_ws, size_t ws_size,
                              hipStream_t stream)
{
    const float* lamb = (const float*)d_in[0];
    const float* mu   = (const float*)d_in[1];
    const float* buoy = (const float*)d_in[2];
    const float* amps = (const float*)d_in[3];
    const int*   src  = (const int*)d_in[4];
    const int*   recl = (const int*)d_in[5];
    float* out = (float*)d_out;
    float* ws  = (float*)d_ws;

    init_kernel<<<dim3(512), dim3(256), 0, stream>>>(ws);
    elastic_kernel<<<dim3(NBLK_), dim3(512), 0, stream>>>(lamb, mu, buoy, amps, src, recl, out, ws);
}